// Round 11
// baseline (621.049 us; speedup 1.0000x reference)
//
#include <hip/hip_runtime.h>

typedef __attribute__((ext_vector_type(8))) short short8;
typedef __attribute__((ext_vector_type(4))) float f32x4;
typedef __attribute__((ext_vector_type(16))) float f32x16;
typedef __attribute__((ext_vector_type(4))) unsigned short u16x4;
typedef __attribute__((ext_vector_type(8))) unsigned short u16x8;

#define H 112
#define W 112
#define HP 114
#define WP 114
#define CIN 128
#define COUT 256
#define NPIX (H * W)          // 12544
#define NIMG 32
#define MTOT (NIMG * NPIX)    // 401408
#define PADELEMS ((long)NIMG * HP * WP * CIN)  // 53,231,616
#define NKT 18                // K-tiles: 9 taps x 2 cin-halves of 64

__device__ __forceinline__ unsigned short f2bf(float f) {
    unsigned int u = __builtin_bit_cast(unsigned int, f);
    u += 0x7FFFu + ((u >> 16) & 1u);
    return (unsigned short)(u >> 16);
}

__device__ __forceinline__ void gl2lds16(const void* g, void* l) {
    __builtin_amdgcn_global_load_lds(
        (const __attribute__((address_space(1))) unsigned int*)g,
        (__attribute__((address_space(3))) unsigned int*)l,
        16, 0, 0);
}

// output pixel p -> padded-image linear pixel index
__device__ __forceinline__ int pidx(int p) {
    int n = p / NPIX;
    int r = p - n * NPIX;
    int oh = r / W, ow = r - oh * W;
    return n * (HP * WP) + (oh + 1) * WP + ow + 1;
}

// ---- weights: bf16 {+1,-1}, layout [tap][khalf][cout][cin64] (R2 layout) ----
__global__ void binw2_kernel(const float* __restrict__ kw, unsigned short* __restrict__ bw) {
    int tid = blockIdx.x * 256 + threadIdx.x;
    int c    = tid & 63;
    int cout = (tid >> 6) & 255;
    int kh   = (tid >> 14) & 1;
    int tap  = tid >> 15;
    int cin  = kh * 64 + c;
    float w = kw[(tap * 128 + cin) * 256 + cout];
    bw[tid] = (w >= 0.0f) ? (unsigned short)0x3F80u : (unsigned short)0xBF80u;
}

// ---- x (f32 NHWC) -> zero-padded bf16 [N][114][114][128] ----
__global__ void pad_kernel(const float* __restrict__ x, unsigned short* __restrict__ xp) {
    long tid = (long)blockIdx.x * 256 + threadIdx.x;   // one thread = 8 elems
    if (tid >= PADELEMS / 8) return;
    int c8 = (int)(tid & 15);
    long rem = tid >> 4;
    int wp = (int)(rem % WP); rem /= WP;
    int hp = (int)(rem % HP);
    int n  = (int)(rem / HP);
    u16x8 v = {0, 0, 0, 0, 0, 0, 0, 0};
    if (hp >= 1 && hp <= H && wp >= 1 && wp <= W) {
        const float* s = x + (((long)(n * H + hp - 1) * W + (wp - 1)) * CIN + c8 * 8);
        f32x4 a = *(const f32x4*)s;
        f32x4 b = *(const f32x4*)(s + 4);
        v = (u16x8){ f2bf(a.x), f2bf(a.y), f2bf(a.z), f2bf(a.w),
                     f2bf(b.x), f2bf(b.y), f2bf(b.z), f2bf(b.w) };
    }
    *(u16x8*)(xp + tid * 8) = v;
}

// ---- conv11: 256x256 tile, BK=64, mfma_32x32x16, plane-major LDS dbuf ----
// 8 waves (2M x 4N), wave-tile 128x64 (4x2 tiles of 32x32).
// Counted vmcnt + 2 barriers per K-tile; compiler owns ds_read<->MFMA order.
__global__ __launch_bounds__(512, 2)
void conv11_kernel(const unsigned short* __restrict__ xp, const unsigned short* __restrict__ bw,
                   float* __restrict__ out) {
    // [buf][plane8][row256][8 shorts]: plane = k>>3 within the BK=64 tile.
    __shared__ unsigned short As[2][8 * 256 * 8];   // 2 x 32 KB
    __shared__ unsigned short Bs[2][8 * 256 * 8];   // 2 x 32 KB

    const int tid = threadIdx.x;
    const int bm = (blockIdx.x & 7) * 196 + (blockIdx.x >> 3);  // 1568 = 8*196
    const int lane = tid & 63;
    const int wv = tid >> 6;
    const int wr = wv >> 2;    // 0..1 (M)
    const int wc = wv & 3;     // 0..3 (N)
    const int l31 = lane & 31;
    const int lh = lane >> 5;  // k-half within frag

    // ---- staging: slot s = j*512 + tid (j=0..3): plane = s>>8, row = s&255 ----
    const int srow = tid & 255;
    const int sp0 = tid >> 8;          // planes sp0 + 2*j
    const unsigned short* aptr = xp + (long)pidx(bm * 256 + srow) * CIN;
    const unsigned short* bptr = bw + srow * 64;   // cout = srow, 64 contiguous k

#define STAGE(T, BUF) do {                                                      \
        const int _tap = (T) >> 1, _kh = (T) & 1;                               \
        const int _sh = ((_tap / 3 - 1) * WP + (_tap % 3 - 1)) * CIN            \
                        + _kh * 64;                                             \
        const unsigned short* _bb = bptr + (((_tap * 2 + _kh)) << 14);          \
        _Pragma("unroll")                                                       \
        for (int j = 0; j < 4; ++j) {                                           \
            const int _pl = sp0 + 2 * j;                                        \
            gl2lds16(aptr + _sh + _pl * 8,                                      \
                     &As[BUF][((_pl) * 256 + srow) * 8]);                       \
            gl2lds16(_bb + _pl * 8,                                             \
                     &Bs[BUF][((_pl) * 256 + srow) * 8]);                       \
        }                                                                       \
    } while (0)

    // ---- fragment read offsets (shorts): plane ks*2+lh, row/col + l31 ----
    // A: row = wr*128 + mt*32 + l31 ; B: col = wc*64 + nt*32 + l31
    const int afr0 = lh * 2048 + (wr * 128 + l31) * 8;   // + ks*4096 + mt*256
    const int bfr0 = lh * 2048 + (wc * 64 + l31) * 8;    // + ks*4096 + nt*256

    f32x16 acc[4][2];
#pragma unroll
    for (int mt = 0; mt < 4; ++mt)
#pragma unroll
        for (int nt = 0; nt < 2; ++nt)
            acc[mt][nt] = (f32x16){0.f,0.f,0.f,0.f,0.f,0.f,0.f,0.f,
                                   0.f,0.f,0.f,0.f,0.f,0.f,0.f,0.f};

    STAGE(0, 0);   // prologue: K-tile 0 in flight (8 loads)

#pragma unroll
    for (int t = 0; t < NKT; ++t) {
        const int buf = t & 1;
        if (t < NKT - 1) {
            STAGE(t + 1, buf ^ 1);
            asm volatile("s_waitcnt vmcnt(8)" ::: "memory");  // tile t resident
        } else {
            asm volatile("s_waitcnt vmcnt(0)" ::: "memory");
        }
        __builtin_amdgcn_s_barrier();

        const unsigned short* a = &As[buf][0];
        const unsigned short* b = &Bs[buf][0];
#pragma unroll
        for (int ks = 0; ks < 4; ++ks) {
            short8 bfr[2], afr[4];
#pragma unroll
            for (int nt = 0; nt < 2; ++nt)
                bfr[nt] = *(const short8*)(b + bfr0 + ks * 4096 + nt * 256);
#pragma unroll
            for (int mt = 0; mt < 4; ++mt)
                afr[mt] = *(const short8*)(a + afr0 + ks * 4096 + mt * 256);
#pragma unroll
            for (int mt = 0; mt < 4; ++mt)
#pragma unroll
                for (int nt = 0; nt < 2; ++nt)
                    acc[mt][nt] = __builtin_amdgcn_mfma_f32_32x32x16_bf16(
                        afr[mt], bfr[nt], acc[mt][nt], 0, 0, 0);
        }
        __builtin_amdgcn_s_barrier();   // reads of buf done -> next stage may overwrite
    }
#undef STAGE

    // ---- epilogue: 32x32 C/D layout col=lane&31, row=(reg&3)+8*(reg>>2)+4*(lane>>5) ----
    const long rbase = (long)bm * 256 + wr * 128 + 4 * lh;
    const int cbase = wc * 64 + l31;
#pragma unroll
    for (int mt = 0; mt < 4; ++mt)
#pragma unroll
        for (int nt = 0; nt < 2; ++nt)
#pragma unroll
            for (int r = 0; r < 16; ++r) {
                long row = rbase + mt * 32 + (r & 3) + 8 * (r >> 2);
                out[row * COUT + cbase + nt * 32] = acc[mt][nt][r];
            }
}

// ---------------- fallback (round-1) path: needs no big workspace ----------------
__global__ void binw_kernel(const float* __restrict__ kw, unsigned short* __restrict__ bw) {
    int tid = blockIdx.x * 256 + threadIdx.x;
    int cin5 = tid & 31;
    int cout = (tid >> 5) & 255;
    int kc4  = (tid >> 13) & 3;
    int tap  = tid >> 15;
    int cin  = kc4 * 32 + cin5;
    float w = kw[(tap * 128 + cin) * 256 + cout];
    bw[tid] = (w >= 0.0f) ? (unsigned short)0x3F80u : (unsigned short)0xBF80u;
}

__global__ __launch_bounds__(256, 2)
void conv_fallback_kernel(const float* __restrict__ x, const unsigned short* __restrict__ bw,
                          float* __restrict__ out) {
    __shared__ unsigned short As[128][40];
    __shared__ unsigned short Bs[128][40];
    const int tid = threadIdx.x;
    const int bm = blockIdx.x, bn = blockIdx.y;
    const int lane = tid & 63;
    const int wv = tid >> 6;
    const int wr = wv >> 1, wc = wv & 1;
    const int c4 = (tid & 7) * 4;
    const int rseg = tid >> 3;
    int ohs[4], ows[4], bases[4];
#pragma unroll
    for (int i = 0; i < 4; ++i) {
        int p = bm * 128 + rseg + i * 32;
        int n = p / NPIX;
        int rem = p - n * NPIX;
        int oh = rem / W, ow = rem - oh * W;
        ohs[i] = oh; ows[i] = ow;
        bases[i] = ((n * H + oh) * W + ow) * CIN;
    }
    f32x4 acc[4][4];
#pragma unroll
    for (int m = 0; m < 4; ++m)
#pragma unroll
        for (int n = 0; n < 4; ++n)
            acc[m][n] = (f32x4){0.f, 0.f, 0.f, 0.f};
    const int arow = wr * 64 + (lane & 15);
    const int brow = wc * 64 + (lane & 15);
    const int koff = (lane >> 4) * 8;
    for (int tap = 0; tap < 9; ++tap) {
        const int dh = tap / 3 - 1, dw = tap % 3 - 1;
        const int shift = (dh * W + dw) * CIN;
#pragma unroll
        for (int kc = 0; kc < 4; ++kc) {
            __syncthreads();
#pragma unroll
            for (int i = 0; i < 4; ++i) {
                int ih = ohs[i] + dh, iw = ows[i] + dw;
                bool valid = ((unsigned)ih < (unsigned)H) & ((unsigned)iw < (unsigned)W);
                f32x4 v = {0.f, 0.f, 0.f, 0.f};
                if (valid) v = *(const f32x4*)(x + bases[i] + shift + kc * 32 + c4);
                u16x4 s = { f2bf(v.x), f2bf(v.y), f2bf(v.z), f2bf(v.w) };
                *(u16x4*)&As[rseg + i * 32][c4] = s;
            }
            const unsigned short* bp = bw + tap * 32768 + kc * 8192 + bn * 4096;
#pragma unroll
            for (int j = 0; j < 2; ++j) {
                int idx = tid + j * 256;
                *(u16x8*)&Bs[idx >> 2][(idx & 3) * 8] = *(const u16x8*)(bp + (idx >> 2) * 32 + (idx & 3) * 8);
            }
            __syncthreads();
            short8 af[4], bfr[4];
#pragma unroll
            for (int m = 0; m < 4; ++m)
                af[m] = *(const short8*)&As[arow + m * 16][koff];
#pragma unroll
            for (int n = 0; n < 4; ++n)
                bfr[n] = *(const short8*)&Bs[brow + n * 16][koff];
#pragma unroll
            for (int m = 0; m < 4; ++m)
#pragma unroll
                for (int n = 0; n < 4; ++n)
                    acc[m][n] = __builtin_amdgcn_mfma_f32_16x16x32_bf16(af[m], bfr[n], acc[m][n], 0, 0, 0);
        }
    }
    const long row0 = (long)bm * 128 + wr * 64 + ((lane >> 4) * 4);
    const int col = bn * 128 + wc * 64 + (lane & 15);
#pragma unroll
    for (int m = 0; m < 4; ++m)
#pragma unroll
        for (int n = 0; n < 4; ++n)
#pragma unroll
            for (int j = 0; j < 4; ++j)
                out[(row0 + m * 16 + j) * COUT + col + n * 16] = acc[m][n][j];
}

extern "C" void kernel_launch(void* const* d_in, const int* in_sizes, int n_in,
                              void* d_out, int out_size, void* d_ws, size_t ws_size,
                              hipStream_t stream) {
    const float* x  = (const float*)d_in[0];
    const float* kw = (const float*)d_in[1];
    float* out = (float*)d_out;
    unsigned short* bw = (unsigned short*)d_ws;
    const size_t BW_BYTES = 9 * 2 * 256 * 64 * 2;         // 589,824
    const size_t PAD_BYTES = (size_t)PADELEMS * 2;        // ~106.5 MB

    if (ws_size >= BW_BYTES + PAD_BYTES) {
        binw2_kernel<<<(9 * 2 * 256 * 64) / 256, 256, 0, stream>>>(kw, bw);
        unsigned short* xp = (unsigned short*)((char*)d_ws + BW_BYTES);
        pad_kernel<<<(int)((PADELEMS / 8 + 255) / 256), 256, 0, stream>>>(x, xp);
        conv11_kernel<<<MTOT / 256, 512, 0, stream>>>(xp, bw, out);
    } else {
        binw_kernel<<<(9 * 256 * 128) / 256, 256, 0, stream>>>(kw, bw);
        dim3 grid(MTOT / 128, COUT / 128);
        conv_fallback_kernel<<<grid, 256, 0, stream>>>(x, bw, out);
    }
}

// Round 12
// 405.611 us; speedup vs baseline: 1.5311x; 1.5311x over previous
//
#include <hip/hip_runtime.h>

typedef __attribute__((ext_vector_type(8))) short short8;
typedef __attribute__((ext_vector_type(4))) float f32x4;
typedef __attribute__((ext_vector_type(4))) unsigned short u16x4;
typedef __attribute__((ext_vector_type(8))) unsigned short u16x8;

#define H 112
#define W 112
#define HP 114
#define WP 114
#define CIN 128
#define COUT 256
#define NPIX (H * W)          // 12544
#define NIMG 32
#define MTOT (NIMG * NPIX)    // 401408
#define NPADPIX (NIMG * HP * WP)               // 415,872 padded pixels
#define PADELEMS ((long)NPADPIX * CIN)         // 53,231,616
#define NSTEP 36              // 9 taps x 4 cin-chunks of 32

__device__ __forceinline__ unsigned short f2bf(float f) {
    unsigned int u = __builtin_bit_cast(unsigned int, f);
    u += 0x7FFFu + ((u >> 16) & 1u);
    return (unsigned short)(u >> 16);
}

__device__ __forceinline__ void gl2lds16(const void* g, void* l) {
    __builtin_amdgcn_global_load_lds(
        (const __attribute__((address_space(1))) unsigned int*)g,
        (__attribute__((address_space(3))) unsigned int*)l,
        16, 0, 0);
}

// output pixel p -> padded-image linear pixel index
__device__ __forceinline__ int pidx(int p) {
    int n = p / NPIX;
    int r = p - n * NPIX;
    int oh = r / W, ow = r - oh * W;
    return n * (HP * WP) + (oh + 1) * WP + ow + 1;
}

// ---- weights bf16 {+1,-1}, layout [tap][kc4][q4][cout256][e8] ----
__global__ void binw3_kernel(const float* __restrict__ kw, unsigned short* __restrict__ bw) {
    int tid = blockIdx.x * 256 + threadIdx.x;
    int e    = tid & 7;
    int cout = (tid >> 3) & 255;
    int q    = (tid >> 11) & 3;
    int kc   = (tid >> 13) & 3;
    int tap  = tid >> 15;
    int cin  = kc * 32 + q * 8 + e;
    float w = kw[(tap * 128 + cin) * 256 + cout];
    bw[tid] = (w >= 0.0f) ? (unsigned short)0x3F80u : (unsigned short)0xBF80u;
}

// ---- x (f32 NHWC) -> chunk-major zero-padded bf16: [chunk16][padpix][8] ----
__global__ void pad2_kernel(const float* __restrict__ x, unsigned short* __restrict__ xp) {
    long s = (long)blockIdx.x * 256 + threadIdx.x;    // one slot = 8 elems
    if (s >= (long)16 * NPADPIX) return;
    int c   = (int)(s / NPADPIX);
    int pix = (int)(s - (long)c * NPADPIX);
    int n  = pix / (HP * WP);
    int r  = pix - n * (HP * WP);
    int hp = r / WP, wp = r - hp * WP;
    u16x8 v = {0, 0, 0, 0, 0, 0, 0, 0};
    if (hp >= 1 && hp <= H && wp >= 1 && wp <= W) {
        const float* src = x + (((long)(n * H + hp - 1) * W + (wp - 1)) * CIN + c * 8);
        f32x4 a = *(const f32x4*)src;
        f32x4 b = *(const f32x4*)(src + 4);
        v = (u16x8){ f2bf(a.x), f2bf(a.y), f2bf(a.z), f2bf(a.w),
                     f2bf(b.x), f2bf(b.y), f2bf(b.z), f2bf(b.w) };
    }
    *(u16x8*)(xp + s * 8) = v;
}

// ---- conv12: 256x256 tile, BK=32, 4-deep LDS ring, plane-major coalesced ----
// 8 waves (2M x 4N), wave-tile 128x64. Stage step t+3 at step t (vmcnt(8) ~
// 2.5 steps slack); ONE barrier per step; compiler owns ds_read<->MFMA order.
__global__ __launch_bounds__(512, 2)
void conv12_kernel(const unsigned short* __restrict__ xp, const unsigned short* __restrict__ bw,
                   float* __restrict__ out) {
    // [buf][plane4][row256][8 shorts] = 16KB per buf per operand
    __shared__ unsigned short As[4][4 * 256 * 8];   // 64 KB
    __shared__ unsigned short Bs[4][4 * 256 * 8];   // 64 KB

    const int tid = threadIdx.x;
    const int bm = (blockIdx.x & 7) * 196 + (blockIdx.x >> 3);  // 1568 = 8*196
    const int lane = tid & 63;
    const int wv = tid >> 6;
    const int wr = wv >> 2;    // 0..1 (M)
    const int wc = wv & 3;     // 0..3 (N)
    const int l15 = lane & 15;

    // staging coords: thread owns row srow, planes sp and sp+2 (16B each)
    const int srow = tid & 255;
    const int sp = tid >> 8;                       // 0/1
    const int apx = pidx(bm * 256 + srow);         // padded pixel of row srow
    const unsigned short* bwp = bw + srow * 8;     // cout = srow

    // stage step T (tap=T>>2, kc=T&3) into ring buffer BUF: 4 gload_lds/thread
#define STAGE(T, BUF) do {                                                      \
        const int _tap = (T) >> 2, _kc = (T) & 3;                               \
        const int _tsh = (_tap / 3 - 1) * WP + (_tap % 3 - 1);                  \
        gl2lds16(xp + ((long)(_kc * 4 + sp) * NPADPIX + apx + _tsh) * 8,        \
                 &As[BUF][(sp * 256 + srow) * 8]);                              \
        gl2lds16(xp + ((long)(_kc * 4 + sp + 2) * NPADPIX + apx + _tsh) * 8,    \
                 &As[BUF][((sp + 2) * 256 + srow) * 8]);                        \
        gl2lds16(bwp + (((_tap * 4 + _kc) * 4 + sp) * 256) * 8,                 \
                 &Bs[BUF][(sp * 256 + srow) * 8]);                              \
        gl2lds16(bwp + (((_tap * 4 + _kc) * 4 + sp + 2) * 256) * 8,             \
                 &Bs[BUF][((sp + 2) * 256 + srow) * 8]);                        \
    } while (0)

    // fragment read offsets (shorts): plane = lane>>4, +row/col*8
    const int aoff = (lane >> 4) * 2048 + (wr * 128 + l15) * 8;   // + m*128
    const int boff = (lane >> 4) * 2048 + (wc * 64 + l15) * 8;    // + n*128

    f32x4 acc[8][4];
#pragma unroll
    for (int m = 0; m < 8; ++m)
#pragma unroll
        for (int n = 0; n < 4; ++n)
            acc[m][n] = (f32x4){0.f, 0.f, 0.f, 0.f};

    // prologue: steps 0,1,2 in flight (12 loads/thread)
    STAGE(0, 0);
    STAGE(1, 1);
    STAGE(2, 2);

#pragma unroll
    for (int t = 0; t < NSTEP; ++t) {
        const int buf = t & 3;
        if (t < NSTEP - 2)
            asm volatile("s_waitcnt vmcnt(8)" ::: "memory");   // step t's 4 loads done
        else if (t == NSTEP - 2)
            asm volatile("s_waitcnt vmcnt(4)" ::: "memory");
        else
            asm volatile("s_waitcnt vmcnt(0)" ::: "memory");
        __builtin_amdgcn_s_barrier();     // all waves' step-t staging landed;
                                          // all waves done reading buf (t+3)&3
        if (t < NSTEP - 3) STAGE(t + 3, (t + 3) & 3);

        short8 bfr[4], afr[8];
#pragma unroll
        for (int n = 0; n < 4; ++n)
            bfr[n] = *(const short8*)&Bs[buf][boff + n * 128];
#pragma unroll
        for (int m = 0; m < 8; ++m)
            afr[m] = *(const short8*)&As[buf][aoff + m * 128];

        __builtin_amdgcn_s_setprio(1);
#pragma unroll
        for (int m = 0; m < 8; ++m)
#pragma unroll
            for (int n = 0; n < 4; ++n)
                acc[m][n] = __builtin_amdgcn_mfma_f32_16x16x32_bf16(
                    afr[m], bfr[n], acc[m][n], 0, 0, 0);
        __builtin_amdgcn_s_setprio(0);
    }
#undef STAGE

    // ---- epilogue: C/D layout col=lane&15, row=(lane>>4)*4+j (proven) ----
    const long row0 = (long)bm * 256 + wr * 128 + (lane >> 4) * 4;
    const int col = wc * 64 + l15;
#pragma unroll
    for (int m = 0; m < 8; ++m)
#pragma unroll
        for (int n = 0; n < 4; ++n)
#pragma unroll
            for (int j = 0; j < 4; ++j)
                out[(row0 + m * 16 + j) * COUT + col + n * 16] = acc[m][n][j];
}

// ---------------- fallback (round-1) path: needs no big workspace ----------------
__global__ void binw_kernel(const float* __restrict__ kw, unsigned short* __restrict__ bw) {
    int tid = blockIdx.x * 256 + threadIdx.x;
    int cin5 = tid & 31;
    int cout = (tid >> 5) & 255;
    int kc4  = (tid >> 13) & 3;
    int tap  = tid >> 15;
    int cin  = kc4 * 32 + cin5;
    float w = kw[(tap * 128 + cin) * 256 + cout];
    bw[tid] = (w >= 0.0f) ? (unsigned short)0x3F80u : (unsigned short)0xBF80u;
}

__global__ __launch_bounds__(256, 2)
void conv_fallback_kernel(const float* __restrict__ x, const unsigned short* __restrict__ bw,
                          float* __restrict__ out) {
    __shared__ unsigned short As[128][40];
    __shared__ unsigned short Bs[128][40];
    const int tid = threadIdx.x;
    const int bm = blockIdx.x, bn = blockIdx.y;
    const int lane = tid & 63;
    const int wv = tid >> 6;
    const int wr = wv >> 1, wc = wv & 1;
    const int c4 = (tid & 7) * 4;
    const int rseg = tid >> 3;
    int ohs[4], ows[4], bases[4];
#pragma unroll
    for (int i = 0; i < 4; ++i) {
        int p = bm * 128 + rseg + i * 32;
        int n = p / NPIX;
        int rem = p - n * NPIX;
        int oh = rem / W, ow = rem - oh * W;
        ohs[i] = oh; ows[i] = ow;
        bases[i] = ((n * H + oh) * W + ow) * CIN;
    }
    f32x4 acc[4][4];
#pragma unroll
    for (int m = 0; m < 4; ++m)
#pragma unroll
        for (int n = 0; n < 4; ++n)
            acc[m][n] = (f32x4){0.f, 0.f, 0.f, 0.f};
    const int arow = wr * 64 + (lane & 15);
    const int brow = wc * 64 + (lane & 15);
    const int koff = (lane >> 4) * 8;
    for (int tap = 0; tap < 9; ++tap) {
        const int dh = tap / 3 - 1, dw = tap % 3 - 1;
        const int shift = (dh * W + dw) * CIN;
#pragma unroll
        for (int kc = 0; kc < 4; ++kc) {
            __syncthreads();
#pragma unroll
            for (int i = 0; i < 4; ++i) {
                int ih = ohs[i] + dh, iw = ows[i] + dw;
                bool valid = ((unsigned)ih < (unsigned)H) & ((unsigned)iw < (unsigned)W);
                f32x4 v = {0.f, 0.f, 0.f, 0.f};
                if (valid) v = *(const f32x4*)(x + bases[i] + shift + kc * 32 + c4);
                u16x4 s = { f2bf(v.x), f2bf(v.y), f2bf(v.z), f2bf(v.w) };
                *(u16x4*)&As[rseg + i * 32][c4] = s;
            }
            const unsigned short* bp = bw + tap * 32768 + kc * 8192 + bn * 4096;
#pragma unroll
            for (int j = 0; j < 2; ++j) {
                int idx = tid + j * 256;
                *(u16x8*)&Bs[idx >> 2][(idx & 3) * 8] = *(const u16x8*)(bp + (idx >> 2) * 32 + (idx & 3) * 8);
            }
            __syncthreads();
            short8 af[4], bfr[4];
#pragma unroll
            for (int m = 0; m < 4; ++m)
                af[m] = *(const short8*)&As[arow + m * 16][koff];
#pragma unroll
            for (int n = 0; n < 4; ++n)
                bfr[n] = *(const short8*)&Bs[brow + n * 16][koff];
#pragma unroll
            for (int m = 0; m < 4; ++m)
#pragma unroll
                for (int n = 0; n < 4; ++n)
                    acc[m][n] = __builtin_amdgcn_mfma_f32_16x16x32_bf16(af[m], bfr[n], acc[m][n], 0, 0, 0);
        }
    }
    const long row0 = (long)bm * 128 + wr * 64 + ((lane >> 4) * 4);
    const int col = bn * 128 + wc * 64 + (lane & 15);
#pragma unroll
    for (int m = 0; m < 4; ++m)
#pragma unroll
        for (int n = 0; n < 4; ++n)
#pragma unroll
            for (int j = 0; j < 4; ++j)
                out[(row0 + m * 16 + j) * COUT + col + n * 16] = acc[m][n][j];
}

extern "C" void kernel_launch(void* const* d_in, const int* in_sizes, int n_in,
                              void* d_out, int out_size, void* d_ws, size_t ws_size,
                              hipStream_t stream) {
    const float* x  = (const float*)d_in[0];
    const float* kw = (const float*)d_in[1];
    float* out = (float*)d_out;
    unsigned short* bw = (unsigned short*)d_ws;
    const size_t BW_BYTES = 9 * 4 * 4 * 256 * 8 * 2;      // 589,824
    const size_t PAD_BYTES = (size_t)PADELEMS * 2;        // ~106.5 MB

    if (ws_size >= BW_BYTES + PAD_BYTES) {
        binw3_kernel<<<(9 * 4 * 4 * 256 * 8) / 256, 256, 0, stream>>>(kw, bw);
        unsigned short* xp = (unsigned short*)((char*)d_ws + BW_BYTES);
        long slots = (long)16 * NPADPIX;
        pad2_kernel<<<(int)((slots + 255) / 256), 256, 0, stream>>>(x, xp);
        conv12_kernel<<<MTOT / 256, 512, 0, stream>>>(xp, bw, out);
    } else {
        binw_kernel<<<(9 * 256 * 128) / 256, 256, 0, stream>>>(kw, bw);
        dim3 grid(MTOT / 128, COUT / 128);
        conv_fallback_kernel<<<grid, 256, 0, stream>>>(x, bw, out);
    }
}